// Round 21
// baseline (200.302 us; speedup 1.0000x reference)
//
#include <hip/hip_runtime.h>
#include <hip/hip_bf16.h>

#define EMBD 1024
#define HEADS 16
#define DH 64
#define SEQ 2048
#define NBATCH 4
#define TOK (NBATCH*SEQ)

typedef __hip_bfloat16 bf16;
typedef __bf16 bf16x8 __attribute__((ext_vector_type(8)));
typedef float f32x4 __attribute__((ext_vector_type(4)));
typedef float f32x16 __attribute__((ext_vector_type(16)));
typedef unsigned u32x4 __attribute__((ext_vector_type(4)));

// device-global scratch (no ws_size assumptions)
__device__ int g_isf32;
__device__ unsigned short g_Xb[TOK*EMBD];
__device__ unsigned short g_Wb[4][EMBD*EMBD];     // Wq, Wk, Wv, Wo as bf16
__device__ unsigned short g_Q[TOK*EMBD];
__device__ unsigned short g_K[TOK*EMBD];
__device__ unsigned short g_Vt[TOK*EMBD];
__device__ unsigned short g_O[TOK*EMBD];

__device__ __forceinline__ f32x4 mfma16(bf16x8 a, bf16x8 b, f32x4 c) {
    return __builtin_amdgcn_mfma_f32_16x16x32_bf16(a, b, c, 0, 0, 0);
}
__device__ __forceinline__ f32x16 mfma32(bf16x8 a, bf16x8 b, f32x16 c) {
    return __builtin_amdgcn_mfma_f32_32x32x16_bf16(a, b, c, 0, 0, 0);
}

#define GLL16(gp, lp) __builtin_amdgcn_global_load_lds( \
    (__attribute__((address_space(1))) void*)(gp), \
    (__attribute__((address_space(3))) void*)(lp), 16, 0, 0)

#define WAITV8 asm volatile("s_waitcnt vmcnt(8)" ::: "memory")
#define WAITV4 asm volatile("s_waitcnt vmcnt(4)" ::: "memory")
#define WAITV2 asm volatile("s_waitcnt vmcnt(2)" ::: "memory")
#define WAITV0 asm volatile("s_waitcnt vmcnt(0)" ::: "memory")
#define SBAR   asm volatile("s_barrier" ::: "memory")

// ---------------------------------------------------------------------------
// Kernel 0a: dtype detect (f32 vs bf16), as before.
// ---------------------------------------------------------------------------
__global__ void detect_dtype(const unsigned short* __restrict__ Xu) {
    __shared__ int cnt;
    if (threadIdx.x == 0) cnt = 0;
    __syncthreads();
    int local = 0;
    for (int i = threadIdx.x; i < 1024; i += 256) {
        const unsigned e = (Xu[2*i] >> 7) & 0xFF;
        if (e >= 0x68 && e <= 0x86) local++;
    }
    atomicAdd(&cnt, local);
    __syncthreads();
    if (threadIdx.x == 0) g_isf32 = (cnt < 512) ? 1 : 0;
}

// ---------------------------------------------------------------------------
// Kernel 0b: convert (f32 -> bf16 RNE) or copy (bf16) X and 4 W's.
// ---------------------------------------------------------------------------
__global__ void __launch_bounds__(256) cvt_all(
    const void* __restrict__ X, const void* __restrict__ Wq,
    const void* __restrict__ Wk, const void* __restrict__ Wv,
    const void* __restrict__ Wo)
{
    const int NV_X = TOK*EMBD/8;        // 1048576
    const int NV_W = EMBD*EMBD/8;       // 131072 = 2^17
    const long v = (long)blockIdx.x * 256 + threadIdx.x;
    const void* src; unsigned short* dst; long o;
    if (v < NV_X) { src = X; dst = g_Xb; o = v; }
    else {
        const long u = v - NV_X;
        const int wi = (int)(u >> 17);
        o = u & (NV_W - 1);
        src = (wi==0) ? Wq : (wi==1) ? Wk : (wi==2) ? Wv : Wo;
        dst = g_Wb[wi];
    }
    if (g_isf32) {
        const float4* sp = reinterpret_cast<const float4*>(src) + o*2;
        const float4 a = sp[0], b4 = sp[1];
        const float f[8] = {a.x, a.y, a.z, a.w, b4.x, b4.y, b4.z, b4.w};
        unsigned short r[8];
        #pragma unroll
        for (int i = 0; i < 8; ++i) {
            bf16 h = __float2bfloat16(f[i]);
            r[i] = *reinterpret_cast<unsigned short*>(&h);
        }
        *reinterpret_cast<uint4*>(dst + o*8) = *reinterpret_cast<const uint4*>(r);
    } else {
        *reinterpret_cast<uint4*>(dst + o*8) = reinterpret_cast<const uint4*>(src)[o];
    }
}

// ---------------------------------------------------------------------------
// Kernel 1 (r12-exact, champion): fused QKV projection, 128x128 tile, BK=64,
// 4 waves, double-buffered 64 KB LDS (2 blocks/CU) + counted vmcnt(8) + raw
// barriers, both-sides XOR swizzle. 3-D grid (default round-robin keeps each
// XCD's resident cohort at 8 X panels + 8 W panels = 4 MB = L2-fit).
// ---------------------------------------------------------------------------
__global__ void __launch_bounds__(256) qkv_gemm(
    const void* __restrict__ bq, const void* __restrict__ bk,
    const void* __restrict__ bv)
{
    const int z = blockIdx.z;
    const bf16* W    = reinterpret_cast<const bf16*>(g_Wb[z]);
    const void* bias = (z == 0) ? bq : (z == 1) ? bk : bv;
    const bf16* Xb   = reinterpret_cast<const bf16*>(g_Xb);
    const int  isf32 = g_isf32;

    const int tile_m = blockIdx.x * 128;
    const int tile_n = blockIdx.y * 128;
    const int tid  = threadIdx.x;
    const int lane = tid & 63;
    const int w    = tid >> 6;
    const int wr   = w >> 1, wc = w & 1;
    const int g    = lane >> 4, c = lane & 15;
    const int xr   = c >> 1;            // read-side XOR (== (row>>1)&7)

    __shared__ __align__(16) bf16 As[2][128*64];   // 32 KB
    __shared__ __align__(16) bf16 Bs[2][128*64];   // 32 KB

    const bf16* Ab = Xb + tile_m*EMBD;
    const bf16* Bb = W  + tile_n*EMBD;

    f32x4 acc[4][4] = {};

    auto stage = [&](int b, int kt) {
        const int kk = kt*64;
        #pragma unroll
        for (int i = 0; i < 4; ++i) {
            const int li  = i*256 + tid;                 // 0..1023
            const int row = li >> 3;
            const int cs  = ((li & 7) ^ ((li >> 4) & 7)) << 3;  // elems
            GLL16(Ab + row*EMBD + kk + cs, As[b] + li*8);
            GLL16(Bb + row*EMBD + kk + cs, Bs[b] + li*8);
        }
    };

    auto compute = [&](int b) {
        #pragma unroll
        for (int kh = 0; kh < 2; ++kh) {
            const int co = (((kh*4 + g) ^ xr) << 3);     // swizzled chunk, elems
            bf16x8 a[4], bfr[4];
            #pragma unroll
            for (int m = 0; m < 4; ++m)
                a[m] = *reinterpret_cast<const bf16x8*>(
                    As[b] + (wr*64 + m*16 + c)*64 + co);
            #pragma unroll
            for (int n = 0; n < 4; ++n)
                bfr[n] = *reinterpret_cast<const bf16x8*>(
                    Bs[b] + (wc*64 + n*16 + c)*64 + co);
            #pragma unroll
            for (int m = 0; m < 4; ++m)
                #pragma unroll
                for (int n = 0; n < 4; ++n)
                    acc[m][n] = mfma16(a[m], bfr[n], acc[m][n]);
        }
    };

    stage(0, 0);
    stage(1, 1);                       // 16 loads in flight

    int buf = 0;
    for (int kt = 0; kt < 15; ++kt) {
        WAITV8;
        SBAR;
        compute(buf);
        SBAR;
        if (kt + 2 < 16) stage(buf, kt + 2);
        buf ^= 1;
    }
    WAITV0;
    SBAR;
    compute(buf);

    // Q scale = (1/sqrt(EMBD)) * log2(e) so softmax runs in exp2 domain
    const float scale = (z == 0) ? 0.04508422f : 1.0f;
    bf16* Qp = reinterpret_cast<bf16*>(g_Q);
    bf16* Kp = reinterpret_cast<bf16*>(g_K);
    bf16* Vp = reinterpret_cast<bf16*>(g_Vt);

    #pragma unroll
    for (int n = 0; n < 4; ++n) {
        const int col = tile_n + wc*64 + n*16 + c;
        const float bval = isf32 ? reinterpret_cast<const float*>(bias)[col]
                                 : __bfloat162float(reinterpret_cast<const bf16*>(bias)[col]);
        const int h = col >> 6, d = col & 63;
        #pragma unroll
        for (int m = 0; m < 4; ++m) {
            const int row0 = tile_m + wr*64 + m*16 + g*4;
            #pragma unroll
            for (int r = 0; r < 4; ++r) {
                const int row = row0 + r;                 // token index
                const int bb = row >> 11, nn = row & (SEQ-1);
                const bf16 val = __float2bfloat16((acc[m][n][r] + bval) * scale);
                if (z == 0)      Qp[((bb*HEADS + h)*SEQ + nn)*DH + d] = val;
                else if (z == 1) Kp[((bb*HEADS + h)*SEQ + nn)*DH + d] = val;
                else             Vp[((bb*HEADS + h)*DH + d)*SEQ + nn] = val;
            }
        }
    }
}

// ---------------------------------------------------------------------------
// Kernel 2 (r21): flash attention, 8-wave blocks (r20) + TRIPLE-BUFFER ring:
// 3 x 16 KB K/V buffers (48 KB LDS; x2 blocks/CU = 96 <= 160, TLP kept).
// Prefetch distance = 2 full iterations: stage t+3 at end of iter t; wait
// WAITV4 retires exactly tile t (2 loads/thread/tile; t+1,t+2 stay in
// flight). Tail: WAITV2 at NT-2, WAITV0 at NT-1. Buffer (t+3)%3 == buf is
// re-staged only after the trailing SBAR fences all reads. BK and slot map
// unchanged (r17's failure mode avoided). Numerics byte-identical.
// ---------------------------------------------------------------------------
__device__ __forceinline__ unsigned pk2(float lo, float hi) {
    unsigned r;
    asm("v_cvt_pk_bf16_f32 %0, %1, %2" : "=v"(r) : "v"(lo), "v"(hi));
    return r;
}

__global__ void __launch_bounds__(512) attn_kernel()
{
    const int n   = blockIdx.x;
    const int xcd = n & 7, j = n >> 3;           // j in 0..63
    const int bh  = xcd*8 + (j >> 3);            // head for this XCD chunk
    const int qt  = j & 7;                       // 256-row q-tile within head
    const int tid = threadIdx.x, lane = tid & 63, wv = tid >> 6;  // wv 0..7
    const int ql = lane & 31, hi = lane >> 5;
    const int q0 = qt*256 + wv*32;               // each wave owns 32 q rows

    const bf16* Qh = reinterpret_cast<const bf16*>(g_Q)  + bh*SEQ*DH;
    const bf16* Kh = reinterpret_cast<const bf16*>(g_K)  + bh*SEQ*DH;
    const bf16* Vh = reinterpret_cast<const bf16*>(g_Vt) + bh*DH*SEQ;
    bf16*       Oh = reinterpret_cast<bf16*>(g_O)        + bh*SEQ*DH;

    __shared__ __align__(16) bf16 Ks[3][4096];
    __shared__ __align__(16) bf16 Vs[3][4096];

    bf16x8 qf[4];
    #pragma unroll
    for (int sd = 0; sd < 4; ++sd)
        qf[sd] = *reinterpret_cast<const bf16x8*>(Qh + (q0 + ql)*DH + sd*16 + hi*8);

    f32x16 minit;
    #pragma unroll
    for (int r = 0; r < 16; ++r) minit[r] = -16.0f;

    // all-ones bf16 A-fragment for the lsum MFMA
    const u32x4 onesw = {0x3F803F80u, 0x3F803F80u, 0x3F803F80u, 0x3F803F80u};
    const bf16x8 ones = __builtin_bit_cast(bf16x8, onesw);

    f32x16 oacc[2] = {};
    f32x16 lsacc = {};               // every element converges to full lsum(q)

    // each wave stages exactly its own slot (wv = mt*4 + sd): 2 loads/tile
    const int smt = wv >> 2, ssd = wv & 3;
    auto stage = [&](int b, int kt) {
        GLL16(Kh + (kt + 32*smt + ql)*DH + ssd*16 + hi*8,
              Ks[b] + wv*512 + lane*8);
        GLL16(Vh + (32*smt + ql)*SEQ + kt + ssd*16 + hi*8,
              Vs[b] + wv*512 + lane*8);
    };

    stage(0, 0);
    stage(1, 64);
    stage(2, 128);                   // 6 loads in flight per thread

    const int NT = SEQ/64;           // 32
    int buf = 0;
    for (int t = 0; t < NT; ++t) {
        if (t < NT - 2)      { WAITV4; }   // retire exactly tile t's 2 loads
        else if (t == NT - 2){ WAITV2; }
        else                 { WAITV0; }
        SBAR;                        // all waves' tile-t slots landed

        #pragma unroll
        for (int st = 0; st < 2; ++st) {
            f32x16 s = minit;
            __builtin_amdgcn_s_setprio(1);
            #pragma unroll
            for (int sd = 0; sd < 4; ++sd) {
                bf16x8 kf = *reinterpret_cast<const bf16x8*>(
                    Ks[buf] + (st*4 + sd)*512 + lane*8);
                s = mfma32(kf, qf[sd], s);
            }
            __builtin_amdgcn_s_setprio(0);

            #pragma unroll
            for (int r = 0; r < 16; ++r) s[r] = __builtin_amdgcn_exp2f(s[r]);

            bf16x8 pb[2];
            #pragma unroll
            for (int jj = 0; jj < 2; ++jj) {
                const int b0 = jj*2, b1 = jj*2 + 1;
                unsigned x0 = pk2(s[4*b0+0], s[4*b0+1]);
                unsigned y0 = pk2(s[4*b1+0], s[4*b1+1]);
                asm("v_permlane32_swap_b32 %0, %1" : "+v"(x0), "+v"(y0));
                unsigned x1 = pk2(s[4*b0+2], s[4*b0+3]);
                unsigned y1 = pk2(s[4*b1+2], s[4*b1+3]);
                asm("v_permlane32_swap_b32 %0, %1" : "+v"(x1), "+v"(y1));
                u32x4 wvec = {x0, x1, y0, y1};
                pb[jj] = __builtin_bit_cast(bf16x8, wvec);
            }

            __builtin_amdgcn_s_setprio(1);
            #pragma unroll
            for (int mt = 0; mt < 2; ++mt)
                #pragma unroll
                for (int jj = 0; jj < 2; ++jj) {
                    bf16x8 vf = *reinterpret_cast<const bf16x8*>(
                        Vs[buf] + (mt*4 + st*2 + jj)*512 + lane*8);
                    oacc[mt] = mfma32(vf, pb[jj], oacc[mt]);
                }
            lsacc = mfma32(ones, pb[0], lsacc);          // row-sum of P, free
            lsacc = mfma32(ones, pb[1], lsacc);          // on the matrix pipe
            __builtin_amdgcn_s_setprio(0);
        }

        SBAR;                        // all waves done reading buf
        if (t + 3 < NT) stage(buf, (t + 3)*64);
        buf = (buf == 2) ? 0 : buf + 1;
    }

    const float inv = 1.0f / lsacc[0];   // reduction completed inside MFMA
    #pragma unroll
    for (int mt = 0; mt < 2; ++mt) {
        #pragma unroll
        for (int b = 0; b < 4; ++b) {
            const int d0 = 32*mt + 8*b + 4*hi;
            unsigned short r4[4];
            #pragma unroll
            for (int t = 0; t < 4; ++t) {
                bf16 h = __float2bfloat16(oacc[mt][4*b + t] * inv);
                r4[t] = *reinterpret_cast<unsigned short*>(&h);
            }
            *reinterpret_cast<ushort4*>(Oh + (q0 + ql)*DH + d0) =
                *reinterpret_cast<const ushort4*>(r4);
        }
    }
}

// ---------------------------------------------------------------------------
// Kernel 3 (r13-exact, champion): output projection, r12 qkv structure:
// 128x128 tile, double-buffered LDS, counted vmcnt(8) + raw barriers,
// both-sides swizzle.
// ---------------------------------------------------------------------------
__global__ void __launch_bounds__(256) out_gemm(
    const void* __restrict__ bo, void* __restrict__ Out)
{
    const bf16* Oin = reinterpret_cast<const bf16*>(g_O);
    const bf16* Wo  = reinterpret_cast<const bf16*>(g_Wb[3]);
    const int isf32 = g_isf32;

    const int tile_m = blockIdx.x * 128;
    const int tile_n = blockIdx.y * 128;
    const int tid  = threadIdx.x;
    const int lane = tid & 63;
    const int w    = tid >> 6;
    const int wr   = w >> 1, wc = w & 1;
    const int g    = lane >> 4, c = lane & 15;
    const int xr   = c >> 1;

    __shared__ __align__(16) bf16 As[2][128*64];
    __shared__ __align__(16) bf16 Bs[2][128*64];

    const bf16* Bb = Wo + tile_n*EMBD;

    f32x4 acc[4][4] = {};

    auto stage = [&](int b, int kt) {
        const bf16* Ab = Oin + ((((unsigned)tile_m >> 11)*HEADS + kt)*SEQ
                                + (tile_m & (SEQ-1)))*DH;
        const int kk = kt*64;
        #pragma unroll
        for (int i = 0; i < 4; ++i) {
            const int li  = i*256 + tid;
            const int row = li >> 3;
            const int cs  = ((li & 7) ^ ((li >> 4) & 7)) << 3;
            GLL16(Ab + row*64 + cs, As[b] + li*8);
            GLL16(Bb + row*EMBD + kk + cs, Bs[b] + li*8);
        }
    };

    auto compute = [&](int b) {
        #pragma unroll
        for (int kh = 0; kh < 2; ++kh) {
            const int co = (((kh*4 + g) ^ xr) << 3);
            bf16x8 a[4], bfr[4];
            #pragma unroll
            for (int m = 0; m < 4; ++m)
                a[m] = *reinterpret_cast<const bf16x8*>(
                    As[b] + (wr*64 + m*16 + c)*64 + co);
            #pragma unroll
            for (int n = 0; n < 4; ++n)
                bfr[n] = *reinterpret_cast<const bf16x8*>(
                    Bs[b] + (wc*64 + n*16 + c)*64 + co);
            #pragma unroll
            for (int m = 0; m < 4; ++m)
                #pragma unroll
                for (int n = 0; n < 4; ++n)
                    acc[m][n] = mfma16(a[m], bfr[n], acc[m][n]);
        }
    };

    stage(0, 0);
    stage(1, 1);

    int buf = 0;
    for (int kt = 0; kt < 15; ++kt) {
        WAITV8;
        SBAR;
        compute(buf);
        SBAR;
        if (kt + 2 < 16) stage(buf, kt + 2);
        buf ^= 1;
    }
    WAITV0;
    SBAR;
    compute(buf);

    #pragma unroll
    for (int n = 0; n < 4; ++n) {
        const int col = tile_n + wc*64 + n*16 + c;
        const float bval = isf32 ? reinterpret_cast<const float*>(bo)[col]
                                 : __bfloat162float(reinterpret_cast<const bf16*>(bo)[col]);
        #pragma unroll
        for (int m = 0; m < 4; ++m) {
            const int row0 = tile_m + wr*64 + m*16 + g*4;
            #pragma unroll
            for (int r = 0; r < 4; ++r) {
                const float val = acc[m][n][r] + bval;
                const int idx = (row0 + r)*EMBD + col;
                if (isf32) reinterpret_cast<float*>(Out)[idx] = val;
                else       reinterpret_cast<bf16*>(Out)[idx] = __float2bfloat16(val);
            }
        }
    }
}

// ---------------------------------------------------------------------------
extern "C" void kernel_launch(void* const* d_in, const int* in_sizes, int n_in,
                              void* d_out, int out_size, void* d_ws, size_t ws_size,
                              hipStream_t stream) {
    (void)in_sizes; (void)n_in; (void)out_size; (void)d_ws; (void)ws_size;
    const void* X  = d_in[0];
    const void* Wq = d_in[1];
    const void* bq = d_in[2];
    const void* Wk = d_in[3];
    const void* bk = d_in[4];
    const void* Wv = d_in[5];
    const void* bv = d_in[6];
    const void* Wo = d_in[7];
    const void* bo = d_in[8];

    detect_dtype<<<dim3(1), dim3(256), 0, stream>>>((const unsigned short*)X);
    cvt_all<<<dim3((TOK*EMBD/8 + 4*EMBD*EMBD/8)/256), dim3(256), 0, stream>>>(X, Wq, Wk, Wv, Wo);
    qkv_gemm<<<dim3(TOK/128, EMBD/128, 3), dim3(256), 0, stream>>>(bq, bk, bv);
    attn_kernel<<<dim3(8*NBATCH*HEADS), dim3(512), 0, stream>>>();
    out_gemm<<<dim3(TOK/128, EMBD/128), dim3(256), 0, stream>>>(bo, d_out);
}

// Round 22
// 197.409 us; speedup vs baseline: 1.0147x; 1.0147x over previous
//
#include <hip/hip_runtime.h>
#include <hip/hip_bf16.h>

#define EMBD 1024
#define HEADS 16
#define DH 64
#define SEQ 2048
#define NBATCH 4
#define TOK (NBATCH*SEQ)

typedef __hip_bfloat16 bf16;
typedef __bf16 bf16x8 __attribute__((ext_vector_type(8)));
typedef float f32x4 __attribute__((ext_vector_type(4)));
typedef float f32x16 __attribute__((ext_vector_type(16)));
typedef unsigned u32x4 __attribute__((ext_vector_type(4)));

// device-global scratch (no ws_size assumptions)
__device__ int g_isf32;
__device__ unsigned short g_Xb[TOK*EMBD];
__device__ unsigned short g_Wb[4][EMBD*EMBD];     // Wq, Wk, Wv, Wo as bf16
__device__ unsigned short g_Q[TOK*EMBD];
__device__ unsigned short g_K[TOK*EMBD];
__device__ unsigned short g_Vt[TOK*EMBD];
__device__ unsigned short g_O[TOK*EMBD];

__device__ __forceinline__ f32x4 mfma16(bf16x8 a, bf16x8 b, f32x4 c) {
    return __builtin_amdgcn_mfma_f32_16x16x32_bf16(a, b, c, 0, 0, 0);
}
__device__ __forceinline__ f32x16 mfma32(bf16x8 a, bf16x8 b, f32x16 c) {
    return __builtin_amdgcn_mfma_f32_32x32x16_bf16(a, b, c, 0, 0, 0);
}

#define GLL16(gp, lp) __builtin_amdgcn_global_load_lds( \
    (__attribute__((address_space(1))) void*)(gp), \
    (__attribute__((address_space(3))) void*)(lp), 16, 0, 0)

#define WAITV8 asm volatile("s_waitcnt vmcnt(8)" ::: "memory")
#define WAITV4 asm volatile("s_waitcnt vmcnt(4)" ::: "memory")
#define WAITV2 asm volatile("s_waitcnt vmcnt(2)" ::: "memory")
#define WAITV0 asm volatile("s_waitcnt vmcnt(0)" ::: "memory")
#define SBAR   asm volatile("s_barrier" ::: "memory")

// ---------------------------------------------------------------------------
// Kernel 0a: dtype detect (f32 vs bf16).
// ---------------------------------------------------------------------------
__global__ void detect_dtype(const unsigned short* __restrict__ Xu) {
    __shared__ int cnt;
    if (threadIdx.x == 0) cnt = 0;
    __syncthreads();
    int local = 0;
    for (int i = threadIdx.x; i < 1024; i += 256) {
        const unsigned e = (Xu[2*i] >> 7) & 0xFF;
        if (e >= 0x68 && e <= 0x86) local++;
    }
    atomicAdd(&cnt, local);
    __syncthreads();
    if (threadIdx.x == 0) g_isf32 = (cnt < 512) ? 1 : 0;
}

// ---------------------------------------------------------------------------
// Kernel 0b: convert (f32 -> bf16 RNE) or copy (bf16) X and 4 W's.
// ---------------------------------------------------------------------------
__global__ void __launch_bounds__(256) cvt_all(
    const void* __restrict__ X, const void* __restrict__ Wq,
    const void* __restrict__ Wk, const void* __restrict__ Wv,
    const void* __restrict__ Wo)
{
    const int NV_X = TOK*EMBD/8;        // 1048576
    const int NV_W = EMBD*EMBD/8;       // 131072 = 2^17
    const long v = (long)blockIdx.x * 256 + threadIdx.x;
    const void* src; unsigned short* dst; long o;
    if (v < NV_X) { src = X; dst = g_Xb; o = v; }
    else {
        const long u = v - NV_X;
        const int wi = (int)(u >> 17);
        o = u & (NV_W - 1);
        src = (wi==0) ? Wq : (wi==1) ? Wk : (wi==2) ? Wv : Wo;
        dst = g_Wb[wi];
    }
    if (g_isf32) {
        const float4* sp = reinterpret_cast<const float4*>(src) + o*2;
        const float4 a = sp[0], b4 = sp[1];
        const float f[8] = {a.x, a.y, a.z, a.w, b4.x, b4.y, b4.z, b4.w};
        unsigned short r[8];
        #pragma unroll
        for (int i = 0; i < 8; ++i) {
            bf16 h = __float2bfloat16(f[i]);
            r[i] = *reinterpret_cast<unsigned short*>(&h);
        }
        *reinterpret_cast<uint4*>(dst + o*8) = *reinterpret_cast<const uint4*>(r);
    } else {
        *reinterpret_cast<uint4*>(dst + o*8) = reinterpret_cast<const uint4*>(src)[o];
    }
}

// ---------------------------------------------------------------------------
// Kernel 1 (r12-exact, champion): fused QKV projection, 128x128 tile, BK=64,
// 4 waves, double-buffered 64 KB LDS (2 blocks/CU) + counted vmcnt(8) + raw
// barriers, both-sides XOR swizzle. 3-D grid (default round-robin keeps each
// XCD's resident cohort at 8 X panels + 8 W panels = 4 MB = L2-fit).
// ---------------------------------------------------------------------------
__global__ void __launch_bounds__(256) qkv_gemm(
    const void* __restrict__ bq, const void* __restrict__ bk,
    const void* __restrict__ bv)
{
    const int z = blockIdx.z;
    const bf16* W    = reinterpret_cast<const bf16*>(g_Wb[z]);
    const void* bias = (z == 0) ? bq : (z == 1) ? bk : bv;
    const bf16* Xb   = reinterpret_cast<const bf16*>(g_Xb);
    const int  isf32 = g_isf32;

    const int tile_m = blockIdx.x * 128;
    const int tile_n = blockIdx.y * 128;
    const int tid  = threadIdx.x;
    const int lane = tid & 63;
    const int w    = tid >> 6;
    const int wr   = w >> 1, wc = w & 1;
    const int g    = lane >> 4, c = lane & 15;
    const int xr   = c >> 1;            // read-side XOR (== (row>>1)&7)

    __shared__ __align__(16) bf16 As[2][128*64];   // 32 KB
    __shared__ __align__(16) bf16 Bs[2][128*64];   // 32 KB

    const bf16* Ab = Xb + tile_m*EMBD;
    const bf16* Bb = W  + tile_n*EMBD;

    f32x4 acc[4][4] = {};

    auto stage = [&](int b, int kt) {
        const int kk = kt*64;
        #pragma unroll
        for (int i = 0; i < 4; ++i) {
            const int li  = i*256 + tid;                 // 0..1023
            const int row = li >> 3;
            const int cs  = ((li & 7) ^ ((li >> 4) & 7)) << 3;  // elems
            GLL16(Ab + row*EMBD + kk + cs, As[b] + li*8);
            GLL16(Bb + row*EMBD + kk + cs, Bs[b] + li*8);
        }
    };

    auto compute = [&](int b) {
        #pragma unroll
        for (int kh = 0; kh < 2; ++kh) {
            const int co = (((kh*4 + g) ^ xr) << 3);     // swizzled chunk, elems
            bf16x8 a[4], bfr[4];
            #pragma unroll
            for (int m = 0; m < 4; ++m)
                a[m] = *reinterpret_cast<const bf16x8*>(
                    As[b] + (wr*64 + m*16 + c)*64 + co);
            #pragma unroll
            for (int n = 0; n < 4; ++n)
                bfr[n] = *reinterpret_cast<const bf16x8*>(
                    Bs[b] + (wc*64 + n*16 + c)*64 + co);
            #pragma unroll
            for (int m = 0; m < 4; ++m)
                #pragma unroll
                for (int n = 0; n < 4; ++n)
                    acc[m][n] = mfma16(a[m], bfr[n], acc[m][n]);
        }
    };

    stage(0, 0);
    stage(1, 1);                       // 16 loads in flight

    int buf = 0;
    for (int kt = 0; kt < 15; ++kt) {
        WAITV8;
        SBAR;
        compute(buf);
        SBAR;
        if (kt + 2 < 16) stage(buf, kt + 2);
        buf ^= 1;
    }
    WAITV0;
    SBAR;
    compute(buf);

    // Q scale = (1/sqrt(EMBD)) * log2(e) so softmax runs in exp2 domain
    const float scale = (z == 0) ? 0.04508422f : 1.0f;
    bf16* Qp = reinterpret_cast<bf16*>(g_Q);
    bf16* Kp = reinterpret_cast<bf16*>(g_K);
    bf16* Vp = reinterpret_cast<bf16*>(g_Vt);

    #pragma unroll
    for (int n = 0; n < 4; ++n) {
        const int col = tile_n + wc*64 + n*16 + c;
        const float bval = isf32 ? reinterpret_cast<const float*>(bias)[col]
                                 : __bfloat162float(reinterpret_cast<const bf16*>(bias)[col]);
        const int h = col >> 6, d = col & 63;
        #pragma unroll
        for (int m = 0; m < 4; ++m) {
            const int row0 = tile_m + wr*64 + m*16 + g*4;
            #pragma unroll
            for (int r = 0; r < 4; ++r) {
                const int row = row0 + r;                 // token index
                const int bb = row >> 11, nn = row & (SEQ-1);
                const bf16 val = __float2bfloat16((acc[m][n][r] + bval) * scale);
                if (z == 0)      Qp[((bb*HEADS + h)*SEQ + nn)*DH + d] = val;
                else if (z == 1) Kp[((bb*HEADS + h)*SEQ + nn)*DH + d] = val;
                else             Vp[((bb*HEADS + h)*DH + d)*SEQ + nn] = val;
            }
        }
    }
}

// ---------------------------------------------------------------------------
// Kernel 2 (r20-exact, champion): flash attention, 8-wave blocks (QBLK=256),
// 32 KB K/V tiles feed 8 waves (per-CU staged bytes halved vs 4-wave),
// 2-buffer counted-vmcnt ring (WAITV2, tail WAITV0), static-shift exp2
// softmax (__builtin_amdgcn_exp2f), lsum-via-MFMA, cvt_pk+permlane pack.
// Grid 512 = 2 blocks/CU; XCD map keeps 8 heads/XCD (4 MB L2-fit).
// ---------------------------------------------------------------------------
__device__ __forceinline__ unsigned pk2(float lo, float hi) {
    unsigned r;
    asm("v_cvt_pk_bf16_f32 %0, %1, %2" : "=v"(r) : "v"(lo), "v"(hi));
    return r;
}

__global__ void __launch_bounds__(512) attn_kernel()
{
    const int n   = blockIdx.x;
    const int xcd = n & 7, j = n >> 3;           // j in 0..63
    const int bh  = xcd*8 + (j >> 3);            // head for this XCD chunk
    const int qt  = j & 7;                       // 256-row q-tile within head
    const int tid = threadIdx.x, lane = tid & 63, wv = tid >> 6;  // wv 0..7
    const int ql = lane & 31, hi = lane >> 5;
    const int q0 = qt*256 + wv*32;               // each wave owns 32 q rows

    const bf16* Qh = reinterpret_cast<const bf16*>(g_Q)  + bh*SEQ*DH;
    const bf16* Kh = reinterpret_cast<const bf16*>(g_K)  + bh*SEQ*DH;
    const bf16* Vh = reinterpret_cast<const bf16*>(g_Vt) + bh*DH*SEQ;
    bf16*       Oh = reinterpret_cast<bf16*>(g_O)        + bh*SEQ*DH;

    __shared__ __align__(16) bf16 Ks[2][4096];
    __shared__ __align__(16) bf16 Vs[2][4096];

    bf16x8 qf[4];
    #pragma unroll
    for (int sd = 0; sd < 4; ++sd)
        qf[sd] = *reinterpret_cast<const bf16x8*>(Qh + (q0 + ql)*DH + sd*16 + hi*8);

    f32x16 minit;
    #pragma unroll
    for (int r = 0; r < 16; ++r) minit[r] = -16.0f;

    // all-ones bf16 A-fragment for the lsum MFMA
    const u32x4 onesw = {0x3F803F80u, 0x3F803F80u, 0x3F803F80u, 0x3F803F80u};
    const bf16x8 ones = __builtin_bit_cast(bf16x8, onesw);

    f32x16 oacc[2] = {};
    f32x16 lsacc = {};               // every element converges to full lsum(q)

    // each wave stages exactly its own slot (wv = mt*4 + sd): 2 loads/tile
    const int smt = wv >> 2, ssd = wv & 3;
    auto stage = [&](int b, int kt) {
        GLL16(Kh + (kt + 32*smt + ql)*DH + ssd*16 + hi*8,
              Ks[b] + wv*512 + lane*8);
        GLL16(Vh + (32*smt + ql)*SEQ + kt + ssd*16 + hi*8,
              Vs[b] + wv*512 + lane*8);
    };

    stage(0, 0);
    stage(1, 64);                    // 4 loads in flight per thread

    const int NT = SEQ/64;           // 32
    int buf = 0;
    for (int t = 0; t < NT; ++t) {
        if (t < NT - 1) { WAITV2; } else { WAITV0; }
        SBAR;                        // all waves' tile-t slots landed

        #pragma unroll
        for (int st = 0; st < 2; ++st) {
            f32x16 s = minit;
            __builtin_amdgcn_s_setprio(1);
            #pragma unroll
            for (int sd = 0; sd < 4; ++sd) {
                bf16x8 kf = *reinterpret_cast<const bf16x8*>(
                    Ks[buf] + (st*4 + sd)*512 + lane*8);
                s = mfma32(kf, qf[sd], s);
            }
            __builtin_amdgcn_s_setprio(0);

            #pragma unroll
            for (int r = 0; r < 16; ++r) s[r] = __builtin_amdgcn_exp2f(s[r]);

            bf16x8 pb[2];
            #pragma unroll
            for (int jj = 0; jj < 2; ++jj) {
                const int b0 = jj*2, b1 = jj*2 + 1;
                unsigned x0 = pk2(s[4*b0+0], s[4*b0+1]);
                unsigned y0 = pk2(s[4*b1+0], s[4*b1+1]);
                asm("v_permlane32_swap_b32 %0, %1" : "+v"(x0), "+v"(y0));
                unsigned x1 = pk2(s[4*b0+2], s[4*b0+3]);
                unsigned y1 = pk2(s[4*b1+2], s[4*b1+3]);
                asm("v_permlane32_swap_b32 %0, %1" : "+v"(x1), "+v"(y1));
                u32x4 wvec = {x0, x1, y0, y1};
                pb[jj] = __builtin_bit_cast(bf16x8, wvec);
            }

            __builtin_amdgcn_s_setprio(1);
            #pragma unroll
            for (int mt = 0; mt < 2; ++mt)
                #pragma unroll
                for (int jj = 0; jj < 2; ++jj) {
                    bf16x8 vf = *reinterpret_cast<const bf16x8*>(
                        Vs[buf] + (mt*4 + st*2 + jj)*512 + lane*8);
                    oacc[mt] = mfma32(vf, pb[jj], oacc[mt]);
                }
            lsacc = mfma32(ones, pb[0], lsacc);          // row-sum of P, free
            lsacc = mfma32(ones, pb[1], lsacc);          // on the matrix pipe
            __builtin_amdgcn_s_setprio(0);
        }

        SBAR;                        // all waves done reading buf
        if (t + 2 < NT) stage(buf, (t + 2)*64);
        buf ^= 1;
    }

    const float inv = 1.0f / lsacc[0];   // reduction completed inside MFMA
    #pragma unroll
    for (int mt = 0; mt < 2; ++mt) {
        #pragma unroll
        for (int b = 0; b < 4; ++b) {
            const int d0 = 32*mt + 8*b + 4*hi;
            unsigned short r4[4];
            #pragma unroll
            for (int t = 0; t < 4; ++t) {
                bf16 h = __float2bfloat16(oacc[mt][4*b + t] * inv);
                r4[t] = *reinterpret_cast<unsigned short*>(&h);
            }
            *reinterpret_cast<ushort4*>(Oh + (q0 + ql)*DH + d0) =
                *reinterpret_cast<const ushort4*>(r4);
        }
    }
}

// ---------------------------------------------------------------------------
// Kernel 3 (r13-exact, champion): output projection, r12 qkv structure:
// 128x128 tile, double-buffered LDS, counted vmcnt(8) + raw barriers,
// both-sides swizzle.
// ---------------------------------------------------------------------------
__global__ void __launch_bounds__(256) out_gemm(
    const void* __restrict__ bo, void* __restrict__ Out)
{
    const bf16* Oin = reinterpret_cast<const bf16*>(g_O);
    const bf16* Wo  = reinterpret_cast<const bf16*>(g_Wb[3]);
    const int isf32 = g_isf32;

    const int tile_m = blockIdx.x * 128;
    const int tile_n = blockIdx.y * 128;
    const int tid  = threadIdx.x;
    const int lane = tid & 63;
    const int w    = tid >> 6;
    const int wr   = w >> 1, wc = w & 1;
    const int g    = lane >> 4, c = lane & 15;
    const int xr   = c >> 1;

    __shared__ __align__(16) bf16 As[2][128*64];
    __shared__ __align__(16) bf16 Bs[2][128*64];

    const bf16* Bb = Wo + tile_n*EMBD;

    f32x4 acc[4][4] = {};

    auto stage = [&](int b, int kt) {
        const bf16* Ab = Oin + ((((unsigned)tile_m >> 11)*HEADS + kt)*SEQ
                                + (tile_m & (SEQ-1)))*DH;
        const int kk = kt*64;
        #pragma unroll
        for (int i = 0; i < 4; ++i) {
            const int li  = i*256 + tid;
            const int row = li >> 3;
            const int cs  = ((li & 7) ^ ((li >> 4) & 7)) << 3;
            GLL16(Ab + row*64 + cs, As[b] + li*8);
            GLL16(Bb + row*EMBD + kk + cs, Bs[b] + li*8);
        }
    };

    auto compute = [&](int b) {
        #pragma unroll
        for (int kh = 0; kh < 2; ++kh) {
            const int co = (((kh*4 + g) ^ xr) << 3);
            bf16x8 a[4], bfr[4];
            #pragma unroll
            for (int m = 0; m < 4; ++m)
                a[m] = *reinterpret_cast<const bf16x8*>(
                    As[b] + (wr*64 + m*16 + c)*64 + co);
            #pragma unroll
            for (int n = 0; n < 4; ++n)
                bfr[n] = *reinterpret_cast<const bf16x8*>(
                    Bs[b] + (wc*64 + n*16 + c)*64 + co);
            #pragma unroll
            for (int m = 0; m < 4; ++m)
                #pragma unroll
                for (int n = 0; n < 4; ++n)
                    acc[m][n] = mfma16(a[m], bfr[n], acc[m][n]);
        }
    };

    stage(0, 0);
    stage(1, 1);

    int buf = 0;
    for (int kt = 0; kt < 15; ++kt) {
        WAITV8;
        SBAR;
        compute(buf);
        SBAR;
        if (kt + 2 < 16) stage(buf, kt + 2);
        buf ^= 1;
    }
    WAITV0;
    SBAR;
    compute(buf);

    #pragma unroll
    for (int n = 0; n < 4; ++n) {
        const int col = tile_n + wc*64 + n*16 + c;
        const float bval = isf32 ? reinterpret_cast<const float*>(bo)[col]
                                 : __bfloat162float(reinterpret_cast<const bf16*>(bo)[col]);
        #pragma unroll
        for (int m = 0; m < 4; ++m) {
            const int row0 = tile_m + wr*64 + m*16 + g*4;
            #pragma unroll
            for (int r = 0; r < 4; ++r) {
                const float val = acc[m][n][r] + bval;
                const int idx = (row0 + r)*EMBD + col;
                if (isf32) reinterpret_cast<float*>(Out)[idx] = val;
                else       reinterpret_cast<bf16*>(Out)[idx] = __float2bfloat16(val);
            }
        }
    }
}

// ---------------------------------------------------------------------------
extern "C" void kernel_launch(void* const* d_in, const int* in_sizes, int n_in,
                              void* d_out, int out_size, void* d_ws, size_t ws_size,
                              hipStream_t stream) {
    (void)in_sizes; (void)n_in; (void)out_size; (void)d_ws; (void)ws_size;
    const void* X  = d_in[0];
    const void* Wq = d_in[1];
    const void* bq = d_in[2];
    const void* Wk = d_in[3];
    const void* bk = d_in[4];
    const void* Wv = d_in[5];
    const void* bv = d_in[6];
    const void* Wo = d_in[7];
    const void* bo = d_in[8];

    detect_dtype<<<dim3(1), dim3(256), 0, stream>>>((const unsigned short*)X);
    cvt_all<<<dim3((TOK*EMBD/8 + 4*EMBD*EMBD/8)/256), dim3(256), 0, stream>>>(X, Wq, Wk, Wv, Wo);
    qkv_gemm<<<dim3(TOK/128, EMBD/128, 3), dim3(256), 0, stream>>>(bq, bk, bv);
    attn_kernel<<<dim3(8*NBATCH*HEADS), dim3(512), 0, stream>>>();
    out_gemm<<<dim3(TOK/128, EMBD/128), dim3(256), 0, stream>>>(bo, d_out);
}